// Round 8
// baseline (169.526 us; speedup 1.0000x reference)
//
#include <hip/hip_runtime.h>
#include <hip/hip_bf16.h>

#define NROWS 10000
#define KPAD  10240

typedef __attribute__((ext_vector_type(8))) short bf16x8;
typedef __attribute__((ext_vector_type(4))) float f32x4;

__device__ __forceinline__ float leaky_f(float x) { return x >= 0.f ? x : 0.01f * x; }

__device__ __forceinline__ unsigned short f2bf(float f) {
    union { float f; unsigned int u; } v; v.f = f;
    unsigned int r = v.u + 0x7fffu + ((v.u >> 16) & 1u);
    return (unsigned short)(r >> 16);
}
__device__ __forceinline__ float bf2f(unsigned short h) {
    union { unsigned int u; float f; } v; v.u = ((unsigned int)h) << 16;
    return v.f;
}

// ---------------- merged weight conversions + zero-init (x handled in gemm_xf32) ----------------
__global__ void conv_all(const float* __restrict__ W1, const float* __restrict__ Wc1a,
                         const float* __restrict__ Wc1b, const float* __restrict__ Wc2a,
                         const float* __restrict__ Wc2b, const float* __restrict__ W6,
                         unsigned short* __restrict__ o1, unsigned short* __restrict__ o2,
                         unsigned short* __restrict__ o3, unsigned short* __restrict__ o4,
                         unsigned short* __restrict__ o5, unsigned short* __restrict__ o6,
                         int* __restrict__ counts, unsigned short* __restrict__ Zt,
                         unsigned short* __restrict__ H2t) {
    int gid = blockIdx.x * 256 + threadIdx.x;
    if (gid < 131072) {                   // W1 512x256
        int i = gid, k = i >> 8, n = i & 255;
        o1[n * 512 + k] = f2bf(W1[i]);
    } else if (gid < 163840) {            // Wc1a 256x128
        int i = gid - 131072, k = i >> 7, n = i & 127;
        o2[n * 256 + k] = f2bf(Wc1a[i]);
    } else if (gid < 172032) {            // Wc1b 128x64
        int i = gid - 163840, k = i >> 6, n = i & 63;
        o3[n * 128 + k] = f2bf(Wc1b[i]);
    } else if (gid < 180224) {            // Wc2a 64x128
        int i = gid - 172032, k = i >> 7, n = i & 127;
        o4[n * 64 + k] = f2bf(Wc2a[i]);
    } else if (gid < 212992) {            // Wc2b 128x256
        int i = gid - 180224, k = i >> 8, n = i & 255;
        o5[n * 128 + k] = f2bf(Wc2b[i]);
    } else if (gid < 344064) {            // W6 256x512
        int i = gid - 212992, k = i >> 9, n = i & 511;
        o6[n * 256 + k] = f2bf(W6[i]);
    } else if (gid < 354064) {
        counts[gid - 344064] = 0;
    } else if (gid < 369424) {            // ZT pad tail [64][10000..10240)
        int i = gid - 354064;
        Zt[(size_t)(i / 240) * KPAD + 10000 + (i % 240)] = 0;
    } else if (gid < 430864) {            // H2T pad tail [256][10000..10240)
        int i = gid - 369424;
        H2t[(size_t)(i / 240) * KPAD + 10000 + (i % 240)] = 0;
    }
}

// ---------------- CSR build ----------------
__global__ void hist_kernel(const int* __restrict__ rows, int* __restrict__ counts, int E) {
    int i = blockIdx.x * blockDim.x + threadIdx.x;
    if (i < E) atomicAdd(&counts[rows[i]], 1);
}

__global__ __launch_bounds__(1024)
void scan_kernel(const int* __restrict__ counts, int* __restrict__ starts,
                 int* __restrict__ cursor, int n) {
    __shared__ int buf[1024];
    int tid = threadIdx.x;
    int base = tid * 10;
    int v[10];
    int local = 0;
#pragma unroll
    for (int j = 0; j < 10; ++j) {
        int i = base + j;
        v[j] = (i < n) ? counts[i] : 0;
        local += v[j];
    }
    buf[tid] = local;
    __syncthreads();
    for (int off = 1; off < 1024; off <<= 1) {
        int t = (tid >= off) ? buf[tid - off] : 0;
        __syncthreads();
        buf[tid] += t;
        __syncthreads();
    }
    int run = buf[tid] - local;
#pragma unroll
    for (int j = 0; j < 10; ++j) {
        int i = base + j;
        if (i < n) { starts[i] = run; cursor[i] = run; run += v[j]; }
    }
    if (tid == 1023) starts[n] = buf[1023];
}

__global__ void scatter_kernel(const int* __restrict__ rows, const int* __restrict__ cols,
                               const float* __restrict__ vals, int* __restrict__ cursor,
                               int* __restrict__ cols_s, float* __restrict__ vals_s, int E) {
    int i = blockIdx.x * blockDim.x + threadIdx.x;
    if (i < E) {
        int pos = atomicAdd(&cursor[rows[i]], 1);
        cols_s[pos] = cols[i];
        vals_s[pos] = vals[i];
    }
}

// ---------------- SpMM: 4 rows/block (1 wave each) for full occupancy ----------------
__global__ __launch_bounds__(256)
void spmm_leaky_kernel(const int* __restrict__ starts, const int* __restrict__ cols_s,
                       const float* __restrict__ vals_s, const unsigned short* __restrict__ C1b,
                       const float* __restrict__ b1, unsigned short* __restrict__ Hb) {
    int r = blockIdx.x * 4 + (threadIdx.x >> 6);
    int t = threadIdx.x & 63;
    float4 a0 = ((const float4*)b1)[t];
    float4 a1 = {0.f, 0.f, 0.f, 0.f};
    float4 a2 = {0.f, 0.f, 0.f, 0.f};
    float4 a3 = {0.f, 0.f, 0.f, 0.f};
    int s = starts[r], e = starts[r + 1];
    int p = s;
    for (; p + 4 <= e; p += 4) {
        int c0 = cols_s[p], c1 = cols_s[p + 1], c2 = cols_s[p + 2], c3 = cols_s[p + 3];
        float v0 = vals_s[p], v1 = vals_s[p + 1], v2 = vals_s[p + 2], v3 = vals_s[p + 3];
        ushort4 s0 = ((const ushort4*)(C1b + (size_t)c0 * 256))[t];
        ushort4 s1 = ((const ushort4*)(C1b + (size_t)c1 * 256))[t];
        ushort4 s2 = ((const ushort4*)(C1b + (size_t)c2 * 256))[t];
        ushort4 s3 = ((const ushort4*)(C1b + (size_t)c3 * 256))[t];
        a0.x += v0 * bf2f(s0.x); a0.y += v0 * bf2f(s0.y);
        a0.z += v0 * bf2f(s0.z); a0.w += v0 * bf2f(s0.w);
        a1.x += v1 * bf2f(s1.x); a1.y += v1 * bf2f(s1.y);
        a1.z += v1 * bf2f(s1.z); a1.w += v1 * bf2f(s1.w);
        a2.x += v2 * bf2f(s2.x); a2.y += v2 * bf2f(s2.y);
        a2.z += v2 * bf2f(s2.z); a2.w += v2 * bf2f(s2.w);
        a3.x += v3 * bf2f(s3.x); a3.y += v3 * bf2f(s3.y);
        a3.z += v3 * bf2f(s3.z); a3.w += v3 * bf2f(s3.w);
    }
    for (; p < e; ++p) {
        int c0 = cols_s[p];
        float v0 = vals_s[p];
        ushort4 s0 = ((const ushort4*)(C1b + (size_t)c0 * 256))[t];
        a0.x += v0 * bf2f(s0.x); a0.y += v0 * bf2f(s0.y);
        a0.z += v0 * bf2f(s0.z); a0.w += v0 * bf2f(s0.w);
    }
    ushort4 h;
    h.x = f2bf(leaky_f(a0.x + a1.x + a2.x + a3.x));
    h.y = f2bf(leaky_f(a0.y + a1.y + a2.y + a3.y));
    h.z = f2bf(leaky_f(a0.z + a1.z + a2.z + a3.z));
    h.w = f2bf(leaky_f(a0.w + a1.w + a2.w + a3.w));
    ((ushort4*)Hb)[(size_t)r * 64 + t] = h;
}

// ---------------- g1: C1 = x(f32) @ W1 -> bf16; BM=128, BN=64, inline f32->bf16 staging ----------------
__global__ __launch_bounds__(256)
void gemm_xf32(const float* __restrict__ A, const unsigned short* __restrict__ Bt,
               unsigned short* __restrict__ Cb, int M, int N, int K) {
    __shared__ short sA[128][72];
    __shared__ short sB[64][72];
    const int bm = blockIdx.x * 128;
    const int bn = blockIdx.y * 64;
    const int tid = threadIdx.x;
    const int lane = tid & 63, wid = tid >> 6;
    const int wm = wid & 1, wn = wid >> 1;
    const int l15 = lane & 15, kg = lane >> 4;

    f32x4 acc[4][2];
#pragma unroll
    for (int i = 0; i < 4; i++)
#pragma unroll
        for (int j = 0; j < 2; j++) acc[i][j] = (f32x4){0.f, 0.f, 0.f, 0.f};

    for (int k0 = 0; k0 < K; k0 += 64) {
        // A: 128 rows x 8 slots (8 bf16/slot); load f32, convert
#pragma unroll
        for (int it = 0; it < 4; ++it) {
            int idx = tid + it * 256;
            int r = idx >> 3, s = idx & 7;
            int gm = bm + r;
            uint4 va = {0u, 0u, 0u, 0u};
            if (gm < M) {
                float4 f0 = *(const float4*)(A + (size_t)gm * K + k0 + s * 8);
                float4 f1 = *(const float4*)(A + (size_t)gm * K + k0 + s * 8 + 4);
                va.x = (unsigned)f2bf(f0.x) | ((unsigned)f2bf(f0.y) << 16);
                va.y = (unsigned)f2bf(f0.z) | ((unsigned)f2bf(f0.w) << 16);
                va.z = (unsigned)f2bf(f1.x) | ((unsigned)f2bf(f1.y) << 16);
                va.w = (unsigned)f2bf(f1.z) | ((unsigned)f2bf(f1.w) << 16);
            }
            *(uint4*)(&sA[r][s * 8]) = va;
        }
#pragma unroll
        for (int it = 0; it < 2; ++it) {
            int idx = tid + it * 256;
            int r = idx >> 3, s = idx & 7;
            *(uint4*)(&sB[r][s * 8]) = *(const uint4*)(Bt + (size_t)(bn + r) * K + k0 + s * 8);
        }
        __syncthreads();
#pragma unroll
        for (int ks = 0; ks < 2; ++ks) {
            bf16x8 a[4], b[2];
#pragma unroll
            for (int i = 0; i < 4; i++)
                a[i] = *(const bf16x8*)(&sA[wm * 64 + i * 16 + l15][kg * 8 + ks * 32]);
#pragma unroll
            for (int j = 0; j < 2; j++)
                b[j] = *(const bf16x8*)(&sB[wn * 32 + j * 16 + l15][kg * 8 + ks * 32]);
#pragma unroll
            for (int i = 0; i < 4; i++)
#pragma unroll
                for (int j = 0; j < 2; j++)
                    acc[i][j] = __builtin_amdgcn_mfma_f32_16x16x32_bf16(a[i], b[j], acc[i][j], 0, 0, 0);
        }
        __syncthreads();
    }
#pragma unroll
    for (int i = 0; i < 4; i++) {
        int row0 = wm * 64 + i * 16 + kg * 4;
#pragma unroll
        for (int j = 0; j < 2; j++) {
            int col = bn + wn * 32 + j * 16 + l15;
#pragma unroll
            for (int r = 0; r < 4; r++) {
                int grow = bm + row0 + r;
                if (grow < M) Cb[(size_t)grow * N + col] = f2bf(acc[i][j][r]);
            }
        }
    }
}

// ---------------- g10: out = A(bf16) @ Bt + bias -> f32; BM=128, BN=64 ----------------
__global__ __launch_bounds__(256)
void gemm128(const unsigned short* __restrict__ A, const unsigned short* __restrict__ Bt,
             const float* __restrict__ bias, float* __restrict__ Cf, int M, int N, int K) {
    __shared__ short sA[128][72];
    __shared__ short sB[64][72];
    const int bm = blockIdx.x * 128;
    const int bn = blockIdx.y * 64;
    const int tid = threadIdx.x;
    const int lane = tid & 63, wid = tid >> 6;
    const int wm = wid & 1, wn = wid >> 1;
    const int l15 = lane & 15, kg = lane >> 4;

    f32x4 acc[4][2];
#pragma unroll
    for (int i = 0; i < 4; i++)
#pragma unroll
        for (int j = 0; j < 2; j++) acc[i][j] = (f32x4){0.f, 0.f, 0.f, 0.f};

    for (int k0 = 0; k0 < K; k0 += 64) {
#pragma unroll
        for (int it = 0; it < 4; ++it) {
            int idx = tid + it * 256;
            int r = idx >> 3, s = idx & 7;
            int gm = bm + r;
            uint4 va = {0u, 0u, 0u, 0u};
            if (gm < M) va = *(const uint4*)(A + (size_t)gm * K + k0 + s * 8);
            *(uint4*)(&sA[r][s * 8]) = va;
        }
#pragma unroll
        for (int it = 0; it < 2; ++it) {
            int idx = tid + it * 256;
            int r = idx >> 3, s = idx & 7;
            *(uint4*)(&sB[r][s * 8]) = *(const uint4*)(Bt + (size_t)(bn + r) * K + k0 + s * 8);
        }
        __syncthreads();
#pragma unroll
        for (int ks = 0; ks < 2; ++ks) {
            bf16x8 a[4], b[2];
#pragma unroll
            for (int i = 0; i < 4; i++)
                a[i] = *(const bf16x8*)(&sA[wm * 64 + i * 16 + l15][kg * 8 + ks * 32]);
#pragma unroll
            for (int j = 0; j < 2; j++)
                b[j] = *(const bf16x8*)(&sB[wn * 32 + j * 16 + l15][kg * 8 + ks * 32]);
#pragma unroll
            for (int i = 0; i < 4; i++)
#pragma unroll
                for (int j = 0; j < 2; j++)
                    acc[i][j] = __builtin_amdgcn_mfma_f32_16x16x32_bf16(a[i], b[j], acc[i][j], 0, 0, 0);
        }
        __syncthreads();
    }
#pragma unroll
    for (int i = 0; i < 4; i++) {
        int row0 = wm * 64 + i * 16 + kg * 4;
#pragma unroll
        for (int j = 0; j < 2; j++) {
            int col = bn + wn * 32 + j * 16 + l15;
            float bv = bias[col];
#pragma unroll
            for (int r = 0; r < 4; r++) {
                int grow = bm + row0 + r;
                if (grow < M) Cf[(size_t)grow * N + col] = acc[i][j][r] + bv;
            }
        }
    }
}

// ---------------- generic 64-tile MFMA GEMM (w6s only) ----------------
template<int ACT, int WF32, int WBF, int WTB>
__global__ __launch_bounds__(256)
void gemm_mfma(const unsigned short* __restrict__ A, const unsigned short* __restrict__ Bt,
               const float* __restrict__ bias, float* __restrict__ Cf,
               unsigned short* __restrict__ Cb, unsigned short* __restrict__ Ct,
               int ldt, int M, int N, int K) {
    __shared__ short sA[64][72];
    __shared__ short sB[64][72];
    const int bm = blockIdx.x * 64;
    const int bn = blockIdx.y * 64;
    const int tid = threadIdx.x;
    const int lane = tid & 63, wid = tid >> 6;
    const int wm = wid & 1, wn = wid >> 1;
    const int l15 = lane & 15, kg = lane >> 4;

    f32x4 acc[2][2];
#pragma unroll
    for (int i = 0; i < 2; i++)
#pragma unroll
        for (int j = 0; j < 2; j++) acc[i][j] = (f32x4){0.f, 0.f, 0.f, 0.f};

    for (int k0 = 0; k0 < K; k0 += 64) {
#pragma unroll
        for (int it = 0; it < 2; ++it) {
            int idx = tid + it * 256;
            int r = idx >> 3, s = idx & 7;
            int gm = bm + r;
            uint4 va = {0u, 0u, 0u, 0u};
            if (gm < M) va = *(const uint4*)(A + (size_t)gm * K + k0 + s * 8);
            *(uint4*)(&sA[r][s * 8]) = va;
            uint4 vb = *(const uint4*)(Bt + (size_t)(bn + r) * K + k0 + s * 8);
            *(uint4*)(&sB[r][s * 8]) = vb;
        }
        __syncthreads();
        bf16x8 a[2][2], b[2][2];
#pragma unroll
        for (int i = 0; i < 2; i++)
#pragma unroll
            for (int ks = 0; ks < 2; ++ks) {
                a[i][ks] = *(const bf16x8*)(&sA[wm * 32 + i * 16 + l15][kg * 8 + ks * 32]);
                b[i][ks] = *(const bf16x8*)(&sB[wn * 32 + i * 16 + l15][kg * 8 + ks * 32]);
            }
#pragma unroll
        for (int ks = 0; ks < 2; ++ks)
#pragma unroll
            for (int i = 0; i < 2; i++)
#pragma unroll
                for (int j = 0; j < 2; j++)
                    acc[i][j] = __builtin_amdgcn_mfma_f32_16x16x32_bf16(a[i][ks], b[j][ks], acc[i][j], 0, 0, 0);
        __syncthreads();
    }

#pragma unroll
    for (int i = 0; i < 2; i++) {
        int row0 = wm * 32 + i * 16 + kg * 4;
#pragma unroll
        for (int j = 0; j < 2; j++) {
            int col = bn + wn * 32 + j * 16 + l15;
            float bv = bias ? bias[col] : 0.f;
            ushort4 tw;
#pragma unroll
            for (int r = 0; r < 4; r++) {
                int grow = bm + row0 + r;
                float v = acc[i][j][r] + bv;
                if (ACT) v = leaky_f(v);
                if (WF32) { if (grow < M) Cf[(size_t)grow * N + col] = v; }
                if (WBF)  { if (grow < M) Cb[(size_t)grow * N + col] = f2bf(v); }
                if (WTB)  ((unsigned short*)&tw)[r] = f2bf(v);
            }
            if (WTB && (bm + row0) < M)
                *(ushort4*)(&Ct[(size_t)col * ldt + bm + row0]) = tw;
        }
    }
}

// ---------------- fused encoder tail: H -> T1 (LDS) -> z ----------------
__global__ __launch_bounds__(256)
void fused_enc(const unsigned short* __restrict__ H,   // [M][256]
               const unsigned short* __restrict__ Wa,  // [128][256]
               const unsigned short* __restrict__ Wb,  // [64][128]
               const float* __restrict__ ba, const float* __restrict__ bb,
               float* __restrict__ Zf, unsigned short* __restrict__ Zb,
               unsigned short* __restrict__ Zt, int M) {
    __shared__ short sA[64][72];
    __shared__ short sB[128][72];
    __shared__ short sT1[64][136];
    __shared__ short sWb[64][136];
    const int bm = blockIdx.x * 64;
    const int tid = threadIdx.x;
    const int lane = tid & 63, wid = tid >> 6;
    const int wm = wid & 1, wn = wid >> 1;
    const int l15 = lane & 15, kg = lane >> 4;

#pragma unroll
    for (int it = 0; it < 4; ++it) {
        int idx = tid + it * 256;
        int r = idx >> 4, s = idx & 15;
        *(uint4*)(&sWb[r][s * 8]) = *(const uint4*)(Wb + r * 128 + s * 8);
    }

    f32x4 accA[2][4];
#pragma unroll
    for (int i = 0; i < 2; i++)
#pragma unroll
        for (int j = 0; j < 4; j++) accA[i][j] = (f32x4){0.f, 0.f, 0.f, 0.f};

    for (int k0 = 0; k0 < 256; k0 += 64) {
#pragma unroll
        for (int it = 0; it < 2; ++it) {
            int idx = tid + it * 256;
            int r = idx >> 3, s = idx & 7;
            int gm = bm + r;
            uint4 va = {0u, 0u, 0u, 0u};
            if (gm < M) va = *(const uint4*)(H + (size_t)gm * 256 + k0 + s * 8);
            *(uint4*)(&sA[r][s * 8]) = va;
        }
#pragma unroll
        for (int it = 0; it < 4; ++it) {
            int idx = tid + it * 256;
            int r = idx >> 3, s = idx & 7;
            *(uint4*)(&sB[r][s * 8]) = *(const uint4*)(Wa + r * 256 + k0 + s * 8);
        }
        __syncthreads();
#pragma unroll
        for (int ks = 0; ks < 2; ++ks) {
            bf16x8 a[2], b[4];
#pragma unroll
            for (int i = 0; i < 2; i++)
                a[i] = *(const bf16x8*)(&sA[wm * 32 + i * 16 + l15][kg * 8 + ks * 32]);
#pragma unroll
            for (int j = 0; j < 4; j++)
                b[j] = *(const bf16x8*)(&sB[wn * 64 + j * 16 + l15][kg * 8 + ks * 32]);
#pragma unroll
            for (int i = 0; i < 2; i++)
#pragma unroll
                for (int j = 0; j < 4; j++)
                    accA[i][j] = __builtin_amdgcn_mfma_f32_16x16x32_bf16(a[i], b[j], accA[i][j], 0, 0, 0);
        }
        __syncthreads();
    }
#pragma unroll
    for (int i = 0; i < 2; i++) {
        int row0 = wm * 32 + i * 16 + kg * 4;
#pragma unroll
        for (int j = 0; j < 4; j++) {
            int col = wn * 64 + j * 16 + l15;
            float bv = ba[col];
#pragma unroll
            for (int r = 0; r < 4; r++)
                sT1[row0 + r][col] = f2bf(leaky_f(accA[i][j][r] + bv));
        }
    }
    __syncthreads();

    f32x4 accB[2][2];
#pragma unroll
    for (int i = 0; i < 2; i++)
#pragma unroll
        for (int j = 0; j < 2; j++) accB[i][j] = (f32x4){0.f, 0.f, 0.f, 0.f};
#pragma unroll
    for (int kc = 0; kc < 4; ++kc) {
        bf16x8 a[2], b[2];
#pragma unroll
        for (int i = 0; i < 2; i++)
            a[i] = *(const bf16x8*)(&sT1[wm * 32 + i * 16 + l15][kc * 32 + kg * 8]);
#pragma unroll
        for (int j = 0; j < 2; j++)
            b[j] = *(const bf16x8*)(&sWb[wn * 32 + j * 16 + l15][kc * 32 + kg * 8]);
#pragma unroll
        for (int i = 0; i < 2; i++)
#pragma unroll
            for (int j = 0; j < 2; j++)
                accB[i][j] = __builtin_amdgcn_mfma_f32_16x16x32_bf16(a[i], b[j], accB[i][j], 0, 0, 0);
    }
#pragma unroll
    for (int i = 0; i < 2; i++) {
        int row0 = wm * 32 + i * 16 + kg * 4;
#pragma unroll
        for (int j = 0; j < 2; j++) {
            int col = wn * 32 + j * 16 + l15;
            float bv = bb[col];
            ushort4 tw;
#pragma unroll
            for (int r = 0; r < 4; r++) {
                int grow = bm + row0 + r;
                float v = accB[i][j][r] + bv;
                if (grow < M) {
                    Zf[(size_t)grow * 64 + col] = v;
                    Zb[(size_t)grow * 64 + col] = f2bf(v);
                }
                ((unsigned short*)&tw)[r] = f2bf(v);
            }
            if ((bm + row0) < M)
                *(ushort4*)(&Zt[(size_t)col * KPAD + bm + row0]) = tw;
        }
    }
}

// ---------------- fused decoder head: z -> T2 (LDS) -> H2^T ----------------
__global__ __launch_bounds__(256)
void fused_dec(const unsigned short* __restrict__ Z,   // [M][64]
               const unsigned short* __restrict__ Wa,  // [128][64]
               const unsigned short* __restrict__ Wb,  // [256][128]
               const float* __restrict__ ba, const float* __restrict__ bb,
               unsigned short* __restrict__ H2t, int M) {
    __shared__ short sA[64][72];
    __shared__ short sB[128][72];
    __shared__ short sT2[64][136];
    __shared__ short sB2[256][72];
    const int bm = blockIdx.x * 64;
    const int tid = threadIdx.x;
    const int lane = tid & 63, wid = tid >> 6;
    const int wm = wid & 1, wn = wid >> 1;
    const int l15 = lane & 15, kg = lane >> 4;

#pragma unroll
    for (int it = 0; it < 2; ++it) {
        int idx = tid + it * 256;
        int r = idx >> 3, s = idx & 7;
        int gm = bm + r;
        uint4 va = {0u, 0u, 0u, 0u};
        if (gm < M) va = *(const uint4*)(Z + (size_t)gm * 64 + s * 8);
        *(uint4*)(&sA[r][s * 8]) = va;
    }
#pragma unroll
    for (int it = 0; it < 4; ++it) {
        int idx = tid + it * 256;
        int r = idx >> 3, s = idx & 7;
        *(uint4*)(&sB[r][s * 8]) = *(const uint4*)(Wa + r * 64 + s * 8);
    }
    __syncthreads();
    f32x4 accA[2][4];
#pragma unroll
    for (int i = 0; i < 2; i++)
#pragma unroll
        for (int j = 0; j < 4; j++) accA[i][j] = (f32x4){0.f, 0.f, 0.f, 0.f};
#pragma unroll
    for (int ks = 0; ks < 2; ++ks) {
        bf16x8 a[2], b[4];
#pragma unroll
        for (int i = 0; i < 2; i++)
            a[i] = *(const bf16x8*)(&sA[wm * 32 + i * 16 + l15][kg * 8 + ks * 32]);
#pragma unroll
        for (int j = 0; j < 4; j++)
            b[j] = *(const bf16x8*)(&sB[wn * 64 + j * 16 + l15][kg * 8 + ks * 32]);
#pragma unroll
        for (int i = 0; i < 2; i++)
#pragma unroll
            for (int j = 0; j < 4; j++)
                accA[i][j] = __builtin_amdgcn_mfma_f32_16x16x32_bf16(a[i], b[j], accA[i][j], 0, 0, 0);
    }
    __syncthreads();
#pragma unroll
    for (int i = 0; i < 2; i++) {
        int row0 = wm * 32 + i * 16 + kg * 4;
#pragma unroll
        for (int j = 0; j < 4; j++) {
            int col = wn * 64 + j * 16 + l15;
            float bv = ba[col];
#pragma unroll
            for (int r = 0; r < 4; r++)
                sT2[row0 + r][col] = f2bf(leaky_f(accA[i][j][r] + bv));
        }
    }
    __syncthreads();

    f32x4 accB[2][8];
#pragma unroll
    for (int i = 0; i < 2; i++)
#pragma unroll
        for (int j = 0; j < 8; j++) accB[i][j] = (f32x4){0.f, 0.f, 0.f, 0.f};
    for (int k0 = 0; k0 < 128; k0 += 64) {
#pragma unroll
        for (int it = 0; it < 8; ++it) {
            int idx = tid + it * 256;
            int r = idx >> 3, s = idx & 7;
            *(uint4*)(&sB2[r][s * 8]) = *(const uint4*)(Wb + r * 128 + k0 + s * 8);
        }
        __syncthreads();
#pragma unroll
        for (int ks = 0; ks < 2; ++ks) {
            bf16x8 a[2], b[8];
#pragma unroll
            for (int i = 0; i < 2; i++)
                a[i] = *(const bf16x8*)(&sT2[wm * 32 + i * 16 + l15][k0 + ks * 32 + kg * 8]);
#pragma unroll
            for (int j = 0; j < 8; j++)
                b[j] = *(const bf16x8*)(&sB2[wn * 128 + j * 16 + l15][kg * 8 + ks * 32]);
#pragma unroll
            for (int i = 0; i < 2; i++)
#pragma unroll
                for (int j = 0; j < 8; j++)
                    accB[i][j] = __builtin_amdgcn_mfma_f32_16x16x32_bf16(a[i], b[j], accB[i][j], 0, 0, 0);
        }
        __syncthreads();
    }
#pragma unroll
    for (int i = 0; i < 2; i++) {
        int row0 = wm * 32 + i * 16 + kg * 4;
#pragma unroll
        for (int j = 0; j < 8; j++) {
            int col = wn * 128 + j * 16 + l15;
            float bv = bb[col];
            ushort4 tw;
#pragma unroll
            for (int r = 0; r < 4; r++)
                ((unsigned short*)&tw)[r] = f2bf(leaky_f(accB[i][j][r] + bv));
            if ((bm + row0) < M)
                *(ushort4*)(&H2t[(size_t)col * KPAD + bm + row0]) = tw;
        }
    }
}

// ---------------- S2 split-K MFMA: 80 splits of 128 ----------------
__global__ __launch_bounds__(256)
void sgemm_sk(const unsigned short* __restrict__ Zt, const unsigned short* __restrict__ H2t,
              float* __restrict__ part) {
    __shared__ short sA[64][72];
    __shared__ short sB[64][72];
    const int bn = blockIdx.x * 64;
    const int kc = blockIdx.y;
    const int tid = threadIdx.x;
    const int lane = tid & 63, wid = tid >> 6;
    const int wm = wid & 1, wn = wid >> 1;
    const int l15 = lane & 15, kg = lane >> 4;

    f32x4 acc[2][2];
#pragma unroll
    for (int i = 0; i < 2; i++)
#pragma unroll
        for (int j = 0; j < 2; j++) acc[i][j] = (f32x4){0.f, 0.f, 0.f, 0.f};

    for (int kk = 0; kk < 2; ++kk) {
        int k0 = kc * 128 + kk * 64;
#pragma unroll
        for (int it = 0; it < 2; ++it) {
            int idx = tid + it * 256;
            int r = idx >> 3, s = idx & 7;
            *(uint4*)(&sA[r][s * 8]) = *(const uint4*)(Zt + (size_t)r * KPAD + k0 + s * 8);
            *(uint4*)(&sB[r][s * 8]) = *(const uint4*)(H2t + (size_t)(bn + r) * KPAD + k0 + s * 8);
        }
        __syncthreads();
        bf16x8 a[2][2], b[2][2];
#pragma unroll
        for (int i = 0; i < 2; i++)
#pragma unroll
            for (int ks = 0; ks < 2; ++ks) {
                a[i][ks] = *(const bf16x8*)(&sA[wm * 32 + i * 16 + l15][kg * 8 + ks * 32]);
                b[i][ks] = *(const bf16x8*)(&sB[wn * 32 + i * 16 + l15][kg * 8 + ks * 32]);
            }
#pragma unroll
        for (int ks = 0; ks < 2; ++ks)
#pragma unroll
            for (int i = 0; i < 2; i++)
#pragma unroll
                for (int j = 0; j < 2; j++)
                    acc[i][j] = __builtin_amdgcn_mfma_f32_16x16x32_bf16(a[i][ks], b[j][ks], acc[i][j], 0, 0, 0);
        __syncthreads();
    }
#pragma unroll
    for (int i = 0; i < 2; i++) {
        int row0 = wm * 32 + i * 16 + kg * 4;
#pragma unroll
        for (int j = 0; j < 2; j++) {
            int col = bn + wn * 32 + j * 16 + l15;
#pragma unroll
            for (int r = 0; r < 4; r++)
                part[((size_t)kc * 64 + row0 + r) * 256 + col] = acc[i][j][r];
        }
    }
}

// reduce 80 partials -> S2 bf16 [64][256]
__global__ void reduce_S2(const float* __restrict__ part, unsigned short* __restrict__ S2b) {
    int i = blockIdx.x * blockDim.x + threadIdx.x;
    if (i < 64 * 256) {
        float s = 0.f;
#pragma unroll
        for (int c = 0; c < 80; ++c) s += part[(size_t)c * (64 * 256) + i];
        S2b[i] = f2bf(s);
    }
}

// ---------------- launch ----------------
extern "C" void kernel_launch(void* const* d_in, const int* in_sizes, int n_in,
                              void* d_out, int out_size, void* d_ws, size_t ws_size,
                              hipStream_t stream) {
    const float* x    = (const float*)d_in[0];
    const int*   rows = (const int*)d_in[1];
    const int*   cols = (const int*)d_in[2];
    const float* vals = (const float*)d_in[3];
    const float* W1   = (const float*)d_in[4];
    const float* b1   = (const float*)d_in[5];
    const float* Wc1a = (const float*)d_in[6];
    const float* bc1a = (const float*)d_in[7];
    const float* Wc1b = (const float*)d_in[8];
    const float* bc1b = (const float*)d_in[9];
    const float* Wc2a = (const float*)d_in[10];
    const float* bc2a = (const float*)d_in[11];
    const float* Wc2b = (const float*)d_in[12];
    const float* bc2b = (const float*)d_in[13];
    const float* W6   = (const float*)d_in[14];
    const float* b6   = (const float*)d_in[15];

    const int N = NROWS;
    const int E = in_sizes[1];

    float* ws = (float*)d_ws;
    unsigned short* C1b  = (unsigned short*)(ws + 2560000);   // [10000][256]
    unsigned short* HHI  = (unsigned short*)(ws + 3840000);   // [10000][256]
    unsigned short* ZHI  = (unsigned short*)(ws + 5120000);   // [10000][64]
    unsigned short* ZT   = (unsigned short*)(ws + 5440000);   // [64][10240]
    unsigned short* H2T  = (unsigned short*)(ws + 5767680);   // [256][10240]
    float*          PART = ws + 7078400;                      // [80][64][256]
    unsigned short* S2B  = (unsigned short*)(ws + 8389120);   // [64][256]
    unsigned short* W6ST = (unsigned short*)(ws + 8397312);   // [512][64]
    unsigned short* W1T   = (unsigned short*)(ws + 8413696);  // [256][512]
    unsigned short* WC1AT = (unsigned short*)(ws + 8479232);  // [128][256]
    unsigned short* WC1BT = (unsigned short*)(ws + 8495616);  // [64][128]
    unsigned short* WC2AT = (unsigned short*)(ws + 8499712);  // [128][64]
    unsigned short* WC2BT = (unsigned short*)(ws + 8503808);  // [256][128]
    unsigned short* W6T   = (unsigned short*)(ws + 8520192);  // [512][256]

    int*   counts = (int*)(ws + 8585728);
    int*   starts = counts + 10000;
    int*   cursor = starts + 10001;
    int*   cols_s = cursor + 10000;
    float* vals_s = (float*)(cols_s + 320000);   // ends ~9.25M floats = 37 MB

    float* Out = (float*)d_out;
    float* Zp  = (float*)d_out + 5120000;

    const int GX = (N + 63) / 64;    // 157
    const int GX128 = (N + 127) / 128; // 79

    conv_all<<<1684, 256, 0, stream>>>(W1, Wc1a, Wc1b, Wc2a, Wc2b, W6,
                                       W1T, WC1AT, WC1BT, WC2AT, WC2BT, W6T,
                                       counts, ZT, H2T);

    hist_kernel<<<(E + 255) / 256, 256, 0, stream>>>(rows, counts, E);
    scan_kernel<<<1, 1024, 0, stream>>>(counts, starts, cursor, N);
    scatter_kernel<<<(E + 255) / 256, 256, 0, stream>>>(rows, cols, vals, cursor, cols_s, vals_s, E);

    // C1 = x @ W1 -> bf16 (f32 A staged+converted inline)
    gemm_xf32<<<dim3(GX128, 4), 256, 0, stream>>>(x, W1T, C1b, N, 256, 512);

    // H = leaky(spmm + b1) -> bf16 (4 rows/block)
    spmm_leaky_kernel<<<N / 4, 256, 0, stream>>>(starts, cols_s, vals_s, C1b, b1, HHI);

    // z = leaky(H@Wc1a+b)@Wc1b + b -> Zp f32, ZHI bf16, ZT bf16
    fused_enc<<<GX, 256, 0, stream>>>(HHI, WC1AT, WC1BT, bc1a, bc1b, Zp, ZHI, ZT, N);

    // H2^T -> bf16 [256][KPAD]
    fused_dec<<<GX, 256, 0, stream>>>(ZHI, WC2AT, WC2BT, bc2a, bc2b, H2T, N);

    // S2 = z^T @ H2 (split-K 80) -> PART -> S2B [64][256]
    sgemm_sk<<<dim3(4, 80), 256, 0, stream>>>(ZT, H2T, PART);
    reduce_S2<<<64, 256, 0, stream>>>(PART, S2B);

    // W6S = S2 @ W6 -> W6ST [512][64]
    gemm_mfma<0,0,0,1><<<dim3(1, 8), 256, 0, stream>>>(S2B, W6T, nullptr,
                                                       nullptr, nullptr, W6ST, 64, 64, 512, 256);

    // out = z @ W6S + b6 -> f32
    gemm128<<<dim3(GX128, 8), 256, 0, stream>>>(ZHI, W6ST, b6, Out, N, 512, 64);
}

// Round 10
// 145.841 us; speedup vs baseline: 1.1624x; 1.1624x over previous
//
#include <hip/hip_runtime.h>
#include <hip/hip_bf16.h>

#define NROWS 10000
#define KPAD  10240

typedef __attribute__((ext_vector_type(8))) short bf16x8;
typedef __attribute__((ext_vector_type(4))) float f32x4;

__device__ __forceinline__ float leaky_f(float x) { return x >= 0.f ? x : 0.01f * x; }

__device__ __forceinline__ unsigned short f2bf(float f) {
    union { float f; unsigned int u; } v; v.f = f;
    unsigned int r = v.u + 0x7fffu + ((v.u >> 16) & 1u);
    return (unsigned short)(r >> 16);
}
__device__ __forceinline__ float bf2f(unsigned short h) {
    union { unsigned int u; float f; } v; v.u = ((unsigned int)h) << 16;
    return v.f;
}

// ---------------- merged conversions + zero-init (round-7 version) ----------------
__global__ void conv_all(const float* __restrict__ x, const float* __restrict__ W1,
                         const float* __restrict__ Wc1a, const float* __restrict__ Wc1b,
                         const float* __restrict__ Wc2a, const float* __restrict__ Wc2b,
                         const float* __restrict__ W6,
                         unsigned short* __restrict__ XHI,
                         unsigned short* __restrict__ o1, unsigned short* __restrict__ o2,
                         unsigned short* __restrict__ o3, unsigned short* __restrict__ o4,
                         unsigned short* __restrict__ o5, unsigned short* __restrict__ o6,
                         int* __restrict__ counts, unsigned short* __restrict__ Zt,
                         unsigned short* __restrict__ H2t) {
    int gid = blockIdx.x * 256 + threadIdx.x;
    if (gid < 1280000) {
        float4 v = ((const float4*)x)[gid];
        ushort4 h;
        h.x = f2bf(v.x); h.y = f2bf(v.y); h.z = f2bf(v.z); h.w = f2bf(v.w);
        ((ushort4*)XHI)[gid] = h;
    } else if (gid < 1411072) {           // W1 512x256
        int i = gid - 1280000, k = i >> 8, n = i & 255;
        o1[n * 512 + k] = f2bf(W1[i]);
    } else if (gid < 1443840) {           // Wc1a 256x128
        int i = gid - 1411072, k = i >> 7, n = i & 127;
        o2[n * 256 + k] = f2bf(Wc1a[i]);
    } else if (gid < 1452032) {           // Wc1b 128x64
        int i = gid - 1443840, k = i >> 6, n = i & 63;
        o3[n * 128 + k] = f2bf(Wc1b[i]);
    } else if (gid < 1460224) {           // Wc2a 64x128
        int i = gid - 1452032, k = i >> 7, n = i & 127;
        o4[n * 64 + k] = f2bf(Wc2a[i]);
    } else if (gid < 1492992) {           // Wc2b 128x256
        int i = gid - 1460224, k = i >> 8, n = i & 255;
        o5[n * 128 + k] = f2bf(Wc2b[i]);
    } else if (gid < 1624064) {           // W6 256x512
        int i = gid - 1492992, k = i >> 9, n = i & 511;
        o6[n * 256 + k] = f2bf(W6[i]);
    } else if (gid < 1634064) {
        counts[gid - 1624064] = 0;
    } else if (gid < 1649424) {           // ZT pad tail [64][10000..10240)
        int i = gid - 1634064;
        Zt[(size_t)(i / 240) * KPAD + 10000 + (i % 240)] = 0;
    } else if (gid < 1710864) {           // H2T pad tail [256][10000..10240)
        int i = gid - 1649424;
        H2t[(size_t)(i / 240) * KPAD + 10000 + (i % 240)] = 0;
    }
}

// ---------------- CSR build ----------------
__global__ void hist_kernel(const int* __restrict__ rows, int* __restrict__ counts, int E) {
    int i = blockIdx.x * blockDim.x + threadIdx.x;
    if (i < E) atomicAdd(&counts[rows[i]], 1);
}

__global__ __launch_bounds__(1024)
void scan_kernel(const int* __restrict__ counts, int* __restrict__ starts,
                 int* __restrict__ cursor, int n) {
    __shared__ int buf[1024];
    int tid = threadIdx.x;
    int base = tid * 10;
    int v[10];
    int local = 0;
#pragma unroll
    for (int j = 0; j < 10; ++j) {
        int i = base + j;
        v[j] = (i < n) ? counts[i] : 0;
        local += v[j];
    }
    buf[tid] = local;
    __syncthreads();
    for (int off = 1; off < 1024; off <<= 1) {
        int t = (tid >= off) ? buf[tid - off] : 0;
        __syncthreads();
        buf[tid] += t;
        __syncthreads();
    }
    int run = buf[tid] - local;
#pragma unroll
    for (int j = 0; j < 10; ++j) {
        int i = base + j;
        if (i < n) { starts[i] = run; cursor[i] = run; run += v[j]; }
    }
    if (tid == 1023) starts[n] = buf[1023];
}

__global__ void scatter_kernel(const int* __restrict__ rows, const int* __restrict__ cols,
                               const float* __restrict__ vals, int* __restrict__ cursor,
                               int* __restrict__ cols_s, float* __restrict__ vals_s, int E) {
    int i = blockIdx.x * blockDim.x + threadIdx.x;
    if (i < E) {
        int pos = atomicAdd(&cursor[rows[i]], 1);
        cols_s[pos] = cols[i];
        vals_s[pos] = vals[i];
    }
}

// ---------------- SpMM (round-7: 64-thread blocks, 1 row/block) ----------------
__global__ __launch_bounds__(64)
void spmm_leaky_kernel(const int* __restrict__ starts, const int* __restrict__ cols_s,
                       const float* __restrict__ vals_s, const unsigned short* __restrict__ C1b,
                       const float* __restrict__ b1, unsigned short* __restrict__ Hb) {
    int r = blockIdx.x;
    int t = threadIdx.x;
    float4 a0 = ((const float4*)b1)[t];
    float4 a1 = {0.f, 0.f, 0.f, 0.f};
    float4 a2 = {0.f, 0.f, 0.f, 0.f};
    float4 a3 = {0.f, 0.f, 0.f, 0.f};
    int s = starts[r], e = starts[r + 1];
    int p = s;
    for (; p + 4 <= e; p += 4) {
        int c0 = cols_s[p], c1 = cols_s[p + 1], c2 = cols_s[p + 2], c3 = cols_s[p + 3];
        float v0 = vals_s[p], v1 = vals_s[p + 1], v2 = vals_s[p + 2], v3 = vals_s[p + 3];
        ushort4 s0 = ((const ushort4*)(C1b + (size_t)c0 * 256))[t];
        ushort4 s1 = ((const ushort4*)(C1b + (size_t)c1 * 256))[t];
        ushort4 s2 = ((const ushort4*)(C1b + (size_t)c2 * 256))[t];
        ushort4 s3 = ((const ushort4*)(C1b + (size_t)c3 * 256))[t];
        a0.x += v0 * bf2f(s0.x); a0.y += v0 * bf2f(s0.y);
        a0.z += v0 * bf2f(s0.z); a0.w += v0 * bf2f(s0.w);
        a1.x += v1 * bf2f(s1.x); a1.y += v1 * bf2f(s1.y);
        a1.z += v1 * bf2f(s1.z); a1.w += v1 * bf2f(s1.w);
        a2.x += v2 * bf2f(s2.x); a2.y += v2 * bf2f(s2.y);
        a2.z += v2 * bf2f(s2.z); a2.w += v2 * bf2f(s2.w);
        a3.x += v3 * bf2f(s3.x); a3.y += v3 * bf2f(s3.y);
        a3.z += v3 * bf2f(s3.z); a3.w += v3 * bf2f(s3.w);
    }
    for (; p < e; ++p) {
        int c0 = cols_s[p];
        float v0 = vals_s[p];
        ushort4 s0 = ((const ushort4*)(C1b + (size_t)c0 * 256))[t];
        a0.x += v0 * bf2f(s0.x); a0.y += v0 * bf2f(s0.y);
        a0.z += v0 * bf2f(s0.z); a0.w += v0 * bf2f(s0.w);
    }
    ushort4 h;
    h.x = f2bf(leaky_f(a0.x + a1.x + a2.x + a3.x));
    h.y = f2bf(leaky_f(a0.y + a1.y + a2.y + a3.y));
    h.z = f2bf(leaky_f(a0.z + a1.z + a2.z + a3.z));
    h.w = f2bf(leaky_f(a0.w + a1.w + a2.w + a3.w));
    ((ushort4*)Hb)[(size_t)r * 64 + t] = h;
}

// ---------------- BM=128 GEMM: bf16 A/Bt; WF32=1: f32 out + bias; WF32=0: bf16 out ----------------
template<int WF32>
__global__ __launch_bounds__(256)
void gemm128(const unsigned short* __restrict__ A, const unsigned short* __restrict__ Bt,
             const float* __restrict__ bias, float* __restrict__ Cf,
             unsigned short* __restrict__ Cb, int M, int N, int K) {
    __shared__ short sA[128][72];
    __shared__ short sB[64][72];
    const int bm = blockIdx.x * 128;
    const int bn = blockIdx.y * 64;
    const int tid = threadIdx.x;
    const int lane = tid & 63, wid = tid >> 6;
    const int wm = wid & 1, wn = wid >> 1;
    const int l15 = lane & 15, kg = lane >> 4;

    f32x4 acc[4][2];
#pragma unroll
    for (int i = 0; i < 4; i++)
#pragma unroll
        for (int j = 0; j < 2; j++) acc[i][j] = (f32x4){0.f, 0.f, 0.f, 0.f};

    for (int k0 = 0; k0 < K; k0 += 64) {
#pragma unroll
        for (int it = 0; it < 4; ++it) {
            int idx = tid + it * 256;
            int r = idx >> 3, s = idx & 7;
            int gm = bm + r;
            uint4 va = {0u, 0u, 0u, 0u};
            if (gm < M) va = *(const uint4*)(A + (size_t)gm * K + k0 + s * 8);
            *(uint4*)(&sA[r][s * 8]) = va;
        }
#pragma unroll
        for (int it = 0; it < 2; ++it) {
            int idx = tid + it * 256;
            int r = idx >> 3, s = idx & 7;
            *(uint4*)(&sB[r][s * 8]) = *(const uint4*)(Bt + (size_t)(bn + r) * K + k0 + s * 8);
        }
        __syncthreads();
#pragma unroll
        for (int ks = 0; ks < 2; ++ks) {
            bf16x8 a[4], b[2];
#pragma unroll
            for (int i = 0; i < 4; i++)
                a[i] = *(const bf16x8*)(&sA[wm * 64 + i * 16 + l15][kg * 8 + ks * 32]);
#pragma unroll
            for (int j = 0; j < 2; j++)
                b[j] = *(const bf16x8*)(&sB[wn * 32 + j * 16 + l15][kg * 8 + ks * 32]);
#pragma unroll
            for (int i = 0; i < 4; i++)
#pragma unroll
                for (int j = 0; j < 2; j++)
                    acc[i][j] = __builtin_amdgcn_mfma_f32_16x16x32_bf16(a[i], b[j], acc[i][j], 0, 0, 0);
        }
        __syncthreads();
    }
#pragma unroll
    for (int i = 0; i < 4; i++) {
        int row0 = wm * 64 + i * 16 + kg * 4;
#pragma unroll
        for (int j = 0; j < 2; j++) {
            int col = bn + wn * 32 + j * 16 + l15;
            float bv = WF32 ? bias[col] : 0.f;
#pragma unroll
            for (int r = 0; r < 4; r++) {
                int grow = bm + row0 + r;
                if (grow < M) {
                    float v = acc[i][j][r] + bv;
                    if (WF32) Cf[(size_t)grow * N + col] = v;
                    else      Cb[(size_t)grow * N + col] = f2bf(v);
                }
            }
        }
    }
}

// ---------------- generic 64-tile MFMA GEMM (w6s only) ----------------
template<int ACT, int WF32, int WBF, int WTB>
__global__ __launch_bounds__(256)
void gemm_mfma(const unsigned short* __restrict__ A, const unsigned short* __restrict__ Bt,
               const float* __restrict__ bias, float* __restrict__ Cf,
               unsigned short* __restrict__ Cb, unsigned short* __restrict__ Ct,
               int ldt, int M, int N, int K) {
    __shared__ short sA[64][72];
    __shared__ short sB[64][72];
    const int bm = blockIdx.x * 64;
    const int bn = blockIdx.y * 64;
    const int tid = threadIdx.x;
    const int lane = tid & 63, wid = tid >> 6;
    const int wm = wid & 1, wn = wid >> 1;
    const int l15 = lane & 15, kg = lane >> 4;

    f32x4 acc[2][2];
#pragma unroll
    for (int i = 0; i < 2; i++)
#pragma unroll
        for (int j = 0; j < 2; j++) acc[i][j] = (f32x4){0.f, 0.f, 0.f, 0.f};

    for (int k0 = 0; k0 < K; k0 += 64) {
#pragma unroll
        for (int it = 0; it < 2; ++it) {
            int idx = tid + it * 256;
            int r = idx >> 3, s = idx & 7;
            int gm = bm + r;
            uint4 va = {0u, 0u, 0u, 0u};
            if (gm < M) va = *(const uint4*)(A + (size_t)gm * K + k0 + s * 8);
            *(uint4*)(&sA[r][s * 8]) = va;
            uint4 vb = *(const uint4*)(Bt + (size_t)(bn + r) * K + k0 + s * 8);
            *(uint4*)(&sB[r][s * 8]) = vb;
        }
        __syncthreads();
        bf16x8 a[2][2], b[2][2];
#pragma unroll
        for (int i = 0; i < 2; i++)
#pragma unroll
            for (int ks = 0; ks < 2; ++ks) {
                a[i][ks] = *(const bf16x8*)(&sA[wm * 32 + i * 16 + l15][kg * 8 + ks * 32]);
                b[i][ks] = *(const bf16x8*)(&sB[wn * 32 + i * 16 + l15][kg * 8 + ks * 32]);
            }
#pragma unroll
        for (int ks = 0; ks < 2; ++ks)
#pragma unroll
            for (int i = 0; i < 2; i++)
#pragma unroll
                for (int j = 0; j < 2; j++)
                    acc[i][j] = __builtin_amdgcn_mfma_f32_16x16x32_bf16(a[i][ks], b[j][ks], acc[i][j], 0, 0, 0);
        __syncthreads();
    }

#pragma unroll
    for (int i = 0; i < 2; i++) {
        int row0 = wm * 32 + i * 16 + kg * 4;
#pragma unroll
        for (int j = 0; j < 2; j++) {
            int col = bn + wn * 32 + j * 16 + l15;
            float bv = bias ? bias[col] : 0.f;
            ushort4 tw;
#pragma unroll
            for (int r = 0; r < 4; r++) {
                int grow = bm + row0 + r;
                float v = acc[i][j][r] + bv;
                if (ACT) v = leaky_f(v);
                if (WF32) { if (grow < M) Cf[(size_t)grow * N + col] = v; }
                if (WBF)  { if (grow < M) Cb[(size_t)grow * N + col] = f2bf(v); }
                if (WTB)  ((unsigned short*)&tw)[r] = f2bf(v);
            }
            if (WTB && (bm + row0) < M)
                *(ushort4*)(&Ct[(size_t)col * ldt + bm + row0]) = tw;
        }
    }
}

// ---------------- fused encoder tail: H -> T1 (LDS) -> z ----------------
__global__ __launch_bounds__(256)
void fused_enc(const unsigned short* __restrict__ H,   // [M][256]
               const unsigned short* __restrict__ Wa,  // [128][256]
               const unsigned short* __restrict__ Wb,  // [64][128]
               const float* __restrict__ ba, const float* __restrict__ bb,
               float* __restrict__ Zf, unsigned short* __restrict__ Zb,
               unsigned short* __restrict__ Zt, int M) {
    __shared__ short sA[64][72];
    __shared__ short sB[128][72];
    __shared__ short sT1[64][136];
    __shared__ short sWb[64][136];
    const int bm = blockIdx.x * 64;
    const int tid = threadIdx.x;
    const int lane = tid & 63, wid = tid >> 6;
    const int wm = wid & 1, wn = wid >> 1;
    const int l15 = lane & 15, kg = lane >> 4;

#pragma unroll
    for (int it = 0; it < 4; ++it) {
        int idx = tid + it * 256;
        int r = idx >> 4, s = idx & 15;
        *(uint4*)(&sWb[r][s * 8]) = *(const uint4*)(Wb + r * 128 + s * 8);
    }

    f32x4 accA[2][4];
#pragma unroll
    for (int i = 0; i < 2; i++)
#pragma unroll
        for (int j = 0; j < 4; j++) accA[i][j] = (f32x4){0.f, 0.f, 0.f, 0.f};

    for (int k0 = 0; k0 < 256; k0 += 64) {
#pragma unroll
        for (int it = 0; it < 2; ++it) {
            int idx = tid + it * 256;
            int r = idx >> 3, s = idx & 7;
            int gm = bm + r;
            uint4 va = {0u, 0u, 0u, 0u};
            if (gm < M) va = *(const uint4*)(H + (size_t)gm * 256 + k0 + s * 8);
            *(uint4*)(&sA[r][s * 8]) = va;
        }
#pragma unroll
        for (int it = 0; it < 4; ++it) {
            int idx = tid + it * 256;
            int r = idx >> 3, s = idx & 7;
            *(uint4*)(&sB[r][s * 8]) = *(const uint4*)(Wa + r * 256 + k0 + s * 8);
        }
        __syncthreads();
#pragma unroll
        for (int ks = 0; ks < 2; ++ks) {
            bf16x8 a[2], b[4];
#pragma unroll
            for (int i = 0; i < 2; i++)
                a[i] = *(const bf16x8*)(&sA[wm * 32 + i * 16 + l15][kg * 8 + ks * 32]);
#pragma unroll
            for (int j = 0; j < 4; j++)
                b[j] = *(const bf16x8*)(&sB[wn * 64 + j * 16 + l15][kg * 8 + ks * 32]);
#pragma unroll
            for (int i = 0; i < 2; i++)
#pragma unroll
                for (int j = 0; j < 4; j++)
                    accA[i][j] = __builtin_amdgcn_mfma_f32_16x16x32_bf16(a[i], b[j], accA[i][j], 0, 0, 0);
        }
        __syncthreads();
    }
#pragma unroll
    for (int i = 0; i < 2; i++) {
        int row0 = wm * 32 + i * 16 + kg * 4;
#pragma unroll
        for (int j = 0; j < 4; j++) {
            int col = wn * 64 + j * 16 + l15;
            float bv = ba[col];
#pragma unroll
            for (int r = 0; r < 4; r++)
                sT1[row0 + r][col] = f2bf(leaky_f(accA[i][j][r] + bv));
        }
    }
    __syncthreads();

    f32x4 accB[2][2];
#pragma unroll
    for (int i = 0; i < 2; i++)
#pragma unroll
        for (int j = 0; j < 2; j++) accB[i][j] = (f32x4){0.f, 0.f, 0.f, 0.f};
#pragma unroll
    for (int kc = 0; kc < 4; ++kc) {
        bf16x8 a[2], b[2];
#pragma unroll
        for (int i = 0; i < 2; i++)
            a[i] = *(const bf16x8*)(&sT1[wm * 32 + i * 16 + l15][kc * 32 + kg * 8]);
#pragma unroll
        for (int j = 0; j < 2; j++)
            b[j] = *(const bf16x8*)(&sWb[wn * 32 + j * 16 + l15][kc * 32 + kg * 8]);
#pragma unroll
        for (int i = 0; i < 2; i++)
#pragma unroll
            for (int j = 0; j < 2; j++)
                accB[i][j] = __builtin_amdgcn_mfma_f32_16x16x32_bf16(a[i], b[j], accB[i][j], 0, 0, 0);
    }
#pragma unroll
    for (int i = 0; i < 2; i++) {
        int row0 = wm * 32 + i * 16 + kg * 4;
#pragma unroll
        for (int j = 0; j < 2; j++) {
            int col = wn * 32 + j * 16 + l15;
            float bv = bb[col];
            ushort4 tw;
#pragma unroll
            for (int r = 0; r < 4; r++) {
                int grow = bm + row0 + r;
                float v = accB[i][j][r] + bv;
                if (grow < M) {
                    Zf[(size_t)grow * 64 + col] = v;
                    Zb[(size_t)grow * 64 + col] = f2bf(v);
                }
                ((unsigned short*)&tw)[r] = f2bf(v);
            }
            if ((bm + row0) < M)
                *(ushort4*)(&Zt[(size_t)col * KPAD + bm + row0]) = tw;
        }
    }
}

// ---------------- fused decoder head: z -> T2 (LDS) -> H2^T ----------------
__global__ __launch_bounds__(256)
void fused_dec(const unsigned short* __restrict__ Z,   // [M][64]
               const unsigned short* __restrict__ Wa,  // [128][64]
               const unsigned short* __restrict__ Wb,  // [256][128]
               const float* __restrict__ ba, const float* __restrict__ bb,
               unsigned short* __restrict__ H2t, int M) {
    __shared__ short sA[64][72];
    __shared__ short sB[128][72];
    __shared__ short sT2[64][136];
    __shared__ short sB2[256][72];
    const int bm = blockIdx.x * 64;
    const int tid = threadIdx.x;
    const int lane = tid & 63, wid = tid >> 6;
    const int wm = wid & 1, wn = wid >> 1;
    const int l15 = lane & 15, kg = lane >> 4;

#pragma unroll
    for (int it = 0; it < 2; ++it) {
        int idx = tid + it * 256;
        int r = idx >> 3, s = idx & 7;
        int gm = bm + r;
        uint4 va = {0u, 0u, 0u, 0u};
        if (gm < M) va = *(const uint4*)(Z + (size_t)gm * 64 + s * 8);
        *(uint4*)(&sA[r][s * 8]) = va;
    }
#pragma unroll
    for (int it = 0; it < 4; ++it) {
        int idx = tid + it * 256;
        int r = idx >> 3, s = idx & 7;
        *(uint4*)(&sB[r][s * 8]) = *(const uint4*)(Wa + r * 64 + s * 8);
    }
    __syncthreads();
    f32x4 accA[2][4];
#pragma unroll
    for (int i = 0; i < 2; i++)
#pragma unroll
        for (int j = 0; j < 4; j++) accA[i][j] = (f32x4){0.f, 0.f, 0.f, 0.f};
#pragma unroll
    for (int ks = 0; ks < 2; ++ks) {
        bf16x8 a[2], b[4];
#pragma unroll
        for (int i = 0; i < 2; i++)
            a[i] = *(const bf16x8*)(&sA[wm * 32 + i * 16 + l15][kg * 8 + ks * 32]);
#pragma unroll
        for (int j = 0; j < 4; j++)
            b[j] = *(const bf16x8*)(&sB[wn * 64 + j * 16 + l15][kg * 8 + ks * 32]);
#pragma unroll
        for (int i = 0; i < 2; i++)
#pragma unroll
            for (int j = 0; j < 4; j++)
                accA[i][j] = __builtin_amdgcn_mfma_f32_16x16x32_bf16(a[i], b[j], accA[i][j], 0, 0, 0);
    }
    __syncthreads();
#pragma unroll
    for (int i = 0; i < 2; i++) {
        int row0 = wm * 32 + i * 16 + kg * 4;
#pragma unroll
        for (int j = 0; j < 4; j++) {
            int col = wn * 64 + j * 16 + l15;
            float bv = ba[col];
#pragma unroll
            for (int r = 0; r < 4; r++)
                sT2[row0 + r][col] = f2bf(leaky_f(accA[i][j][r] + bv));
        }
    }
    __syncthreads();

    f32x4 accB[2][8];
#pragma unroll
    for (int i = 0; i < 2; i++)
#pragma unroll
        for (int j = 0; j < 8; j++) accB[i][j] = (f32x4){0.f, 0.f, 0.f, 0.f};
    for (int k0 = 0; k0 < 128; k0 += 64) {
#pragma unroll
        for (int it = 0; it < 8; ++it) {
            int idx = tid + it * 256;
            int r = idx >> 3, s = idx & 7;
            *(uint4*)(&sB2[r][s * 8]) = *(const uint4*)(Wb + r * 128 + k0 + s * 8);
        }
        __syncthreads();
#pragma unroll
        for (int ks = 0; ks < 2; ++ks) {
            bf16x8 a[2], b[8];
#pragma unroll
            for (int i = 0; i < 2; i++)
                a[i] = *(const bf16x8*)(&sT2[wm * 32 + i * 16 + l15][k0 + ks * 32 + kg * 8]);
#pragma unroll
            for (int j = 0; j < 8; j++)
                b[j] = *(const bf16x8*)(&sB2[wn * 128 + j * 16 + l15][kg * 8 + ks * 32]);
#pragma unroll
            for (int i = 0; i < 2; i++)
#pragma unroll
                for (int j = 0; j < 8; j++)
                    accB[i][j] = __builtin_amdgcn_mfma_f32_16x16x32_bf16(a[i], b[j], accB[i][j], 0, 0, 0);
        }
        __syncthreads();
    }
#pragma unroll
    for (int i = 0; i < 2; i++) {
        int row0 = wm * 32 + i * 16 + kg * 4;
#pragma unroll
        for (int j = 0; j < 8; j++) {
            int col = wn * 128 + j * 16 + l15;
            float bv = bb[col];
            ushort4 tw;
#pragma unroll
            for (int r = 0; r < 4; r++)
                ((unsigned short*)&tw)[r] = f2bf(leaky_f(accB[i][j][r] + bv));
            if ((bm + row0) < M)
                *(ushort4*)(&H2t[(size_t)col * KPAD + bm + row0]) = tw;
        }
    }
}

// ---------------- S2 split-K MFMA: 40 splits of 256 (round-7) ----------------
__global__ __launch_bounds__(256)
void sgemm_sk(const unsigned short* __restrict__ Zt, const unsigned short* __restrict__ H2t,
              float* __restrict__ part) {
    __shared__ short sA[64][72];
    __shared__ short sB[64][72];
    const int bn = blockIdx.x * 64;
    const int kc = blockIdx.y;
    const int tid = threadIdx.x;
    const int lane = tid & 63, wid = tid >> 6;
    const int wm = wid & 1, wn = wid >> 1;
    const int l15 = lane & 15, kg = lane >> 4;

    f32x4 acc[2][2];
#pragma unroll
    for (int i = 0; i < 2; i++)
#pragma unroll
        for (int j = 0; j < 2; j++) acc[i][j] = (f32x4){0.f, 0.f, 0.f, 0.f};

    for (int kk = 0; kk < 4; ++kk) {
        int k0 = kc * 256 + kk * 64;
#pragma unroll
        for (int it = 0; it < 2; ++it) {
            int idx = tid + it * 256;
            int r = idx >> 3, s = idx & 7;
            *(uint4*)(&sA[r][s * 8]) = *(const uint4*)(Zt + (size_t)r * KPAD + k0 + s * 8);
            *(uint4*)(&sB[r][s * 8]) = *(const uint4*)(H2t + (size_t)(bn + r) * KPAD + k0 + s * 8);
        }
        __syncthreads();
        bf16x8 a[2][2], b[2][2];
#pragma unroll
        for (int i = 0; i < 2; i++)
#pragma unroll
            for (int ks = 0; ks < 2; ++ks) {
                a[i][ks] = *(const bf16x8*)(&sA[wm * 32 + i * 16 + l15][kg * 8 + ks * 32]);
                b[i][ks] = *(const bf16x8*)(&sB[wn * 32 + i * 16 + l15][kg * 8 + ks * 32]);
            }
#pragma unroll
        for (int ks = 0; ks < 2; ++ks)
#pragma unroll
            for (int i = 0; i < 2; i++)
#pragma unroll
                for (int j = 0; j < 2; j++)
                    acc[i][j] = __builtin_amdgcn_mfma_f32_16x16x32_bf16(a[i][ks], b[j][ks], acc[i][j], 0, 0, 0);
        __syncthreads();
    }
#pragma unroll
    for (int i = 0; i < 2; i++) {
        int row0 = wm * 32 + i * 16 + kg * 4;
#pragma unroll
        for (int j = 0; j < 2; j++) {
            int col = bn + wn * 32 + j * 16 + l15;
#pragma unroll
            for (int r = 0; r < 4; r++)
                part[((size_t)kc * 64 + row0 + r) * 256 + col] = acc[i][j][r];
        }
    }
}

// reduce 40 partials -> S2 bf16 [64][256]
__global__ void reduce_S2(const float* __restrict__ part, unsigned short* __restrict__ S2b) {
    int i = blockIdx.x * blockDim.x + threadIdx.x;
    if (i < 64 * 256) {
        float s = 0.f;
#pragma unroll
        for (int c = 0; c < 40; ++c) s += part[(size_t)c * (64 * 256) + i];
        S2b[i] = f2bf(s);
    }
}

// ---------------- launch ----------------
extern "C" void kernel_launch(void* const* d_in, const int* in_sizes, int n_in,
                              void* d_out, int out_size, void* d_ws, size_t ws_size,
                              hipStream_t stream) {
    const float* x    = (const float*)d_in[0];
    const int*   rows = (const int*)d_in[1];
    const int*   cols = (const int*)d_in[2];
    const float* vals = (const float*)d_in[3];
    const float* W1   = (const float*)d_in[4];
    const float* b1   = (const float*)d_in[5];
    const float* Wc1a = (const float*)d_in[6];
    const float* bc1a = (const float*)d_in[7];
    const float* Wc1b = (const float*)d_in[8];
    const float* bc1b = (const float*)d_in[9];
    const float* Wc2a = (const float*)d_in[10];
    const float* bc2a = (const float*)d_in[11];
    const float* Wc2b = (const float*)d_in[12];
    const float* bc2b = (const float*)d_in[13];
    const float* W6   = (const float*)d_in[14];
    const float* b6   = (const float*)d_in[15];

    const int N = NROWS;
    const int E = in_sizes[1];

    float* ws = (float*)d_ws;
    unsigned short* XHI  = (unsigned short*)(ws + 0);         // [10000][512]
    unsigned short* C1b  = (unsigned short*)(ws + 2560000);   // [10000][256]
    unsigned short* HHI  = (unsigned short*)(ws + 3840000);   // [10000][256]
    unsigned short* ZHI  = (unsigned short*)(ws + 5120000);   // [10000][64]
    unsigned short* ZT   = (unsigned short*)(ws + 5440000);   // [64][10240]
    unsigned short* H2T  = (unsigned short*)(ws + 5767680);   // [256][10240]
    float*          PART = ws + 7078400;                      // [40][64][256]
    unsigned short* S2B  = (unsigned short*)(ws + 7733760);   // [64][256]
    unsigned short* W6ST = (unsigned short*)(ws + 7741952);   // [512][64]
    unsigned short* W1T   = (unsigned short*)(ws + 7758336);  // [256][512]
    unsigned short* WC1AT = (unsigned short*)(ws + 7823872);  // [128][256]
    unsigned short* WC1BT = (unsigned short*)(ws + 7840256);  // [64][128]
    unsigned short* WC2AT = (unsigned short*)(ws + 7844352);  // [128][64]
    unsigned short* WC2BT = (unsigned short*)(ws + 7848448);  // [256][128]
    unsigned short* W6T   = (unsigned short*)(ws + 7864832);  // [512][256]

    int*   counts = (int*)(ws + 7930368);
    int*   starts = counts + 10000;
    int*   cursor = starts + 10001;
    int*   cols_s = cursor + 10000;
    float* vals_s = (float*)(cols_s + 320000);

    float* Out = (float*)d_out;
    float* Zp  = (float*)d_out + 5120000;

    const int GX = (N + 63) / 64;      // 157
    const int GX128 = (N + 127) / 128; // 79

    conv_all<<<6683, 256, 0, stream>>>(x, W1, Wc1a, Wc1b, Wc2a, Wc2b, W6, XHI,
                                       W1T, WC1AT, WC1BT, WC2AT, WC2BT, W6T,
                                       counts, ZT, H2T);

    hist_kernel<<<(E + 255) / 256, 256, 0, stream>>>(rows, counts, E);
    scan_kernel<<<1, 1024, 0, stream>>>(counts, starts, cursor, N);
    scatter_kernel<<<(E + 255) / 256, 256, 0, stream>>>(rows, cols, vals, cursor, cols_s, vals_s, E);

    // C1 = x @ W1 -> bf16 (BM=128 tile, bf16 A from XHI)
    gemm128<0><<<dim3(GX128, 4), 256, 0, stream>>>(XHI, W1T, nullptr,
                                                   nullptr, C1b, N, 256, 512);

    // H = leaky(spmm + b1) -> bf16 (round-7: 1 row / 64-thread block)
    spmm_leaky_kernel<<<N, 64, 0, stream>>>(starts, cols_s, vals_s, C1b, b1, HHI);

    // z = leaky(H@Wc1a+b)@Wc1b + b -> Zp f32, ZHI bf16, ZT bf16
    fused_enc<<<GX, 256, 0, stream>>>(HHI, WC1AT, WC1BT, bc1a, bc1b, Zp, ZHI, ZT, N);

    // H2^T -> bf16 [256][KPAD]
    fused_dec<<<GX, 256, 0, stream>>>(ZHI, WC2AT, WC2BT, bc2a, bc2b, H2T, N);

    // S2 = z^T @ H2 (split-K 40) -> PART -> S2B [64][256]
    sgemm_sk<<<dim3(4, 40), 256, 0, stream>>>(ZT, H2T, PART);
    reduce_S2<<<64, 256, 0, stream>>>(PART, S2B);

    // W6S = S2 @ W6 -> W6ST [512][64]
    gemm_mfma<0,0,0,1><<<dim3(1, 8), 256, 0, stream>>>(S2B, W6T, nullptr,
                                                       nullptr, nullptr, W6ST, 64, 64, 512, 256);

    // out = z @ W6S + b6 -> f32 (BM=128 tile)
    gemm128<1><<<dim3(GX128, 8), 256, 0, stream>>>(ZHI, W6ST, b6, Out, nullptr, N, 512, 64);
}

// Round 11
// 137.007 us; speedup vs baseline: 1.2374x; 1.0645x over previous
//
#include <hip/hip_runtime.h>
#include <hip/hip_bf16.h>

#define NROWS 10000
#define KPAD  10240

typedef __attribute__((ext_vector_type(8))) short bf16x8;
typedef __attribute__((ext_vector_type(4))) float f32x4;

__device__ __forceinline__ float leaky_f(float x) { return x >= 0.f ? x : 0.01f * x; }

__device__ __forceinline__ unsigned short f2bf(float f) {
    union { float f; unsigned int u; } v; v.f = f;
    unsigned int r = v.u + 0x7fffu + ((v.u >> 16) & 1u);
    return (unsigned short)(r >> 16);
}
__device__ __forceinline__ float bf2f(unsigned short h) {
    union { unsigned int u; float f; } v; v.u = ((unsigned int)h) << 16;
    return v.f;
}

// ---------------- merged conversions + zero-init ----------------
__global__ void conv_all(const float* __restrict__ x, const float* __restrict__ W1,
                         const float* __restrict__ Wc1a, const float* __restrict__ Wc1b,
                         const float* __restrict__ Wc2a, const float* __restrict__ Wc2b,
                         const float* __restrict__ W6,
                         unsigned short* __restrict__ XHI,
                         unsigned short* __restrict__ o1, unsigned short* __restrict__ o2,
                         unsigned short* __restrict__ o3, unsigned short* __restrict__ o4,
                         unsigned short* __restrict__ o5, unsigned short* __restrict__ o6,
                         int* __restrict__ counts, unsigned short* __restrict__ Zt,
                         unsigned short* __restrict__ H2t) {
    int gid = blockIdx.x * 256 + threadIdx.x;
    if (gid < 1280000) {
        float4 v = ((const float4*)x)[gid];
        ushort4 h;
        h.x = f2bf(v.x); h.y = f2bf(v.y); h.z = f2bf(v.z); h.w = f2bf(v.w);
        ((ushort4*)XHI)[gid] = h;
    } else if (gid < 1411072) {           // W1 512x256
        int i = gid - 1280000, k = i >> 8, n = i & 255;
        o1[n * 512 + k] = f2bf(W1[i]);
    } else if (gid < 1443840) {           // Wc1a 256x128
        int i = gid - 1411072, k = i >> 7, n = i & 127;
        o2[n * 256 + k] = f2bf(Wc1a[i]);
    } else if (gid < 1452032) {           // Wc1b 128x64
        int i = gid - 1443840, k = i >> 6, n = i & 63;
        o3[n * 128 + k] = f2bf(Wc1b[i]);
    } else if (gid < 1460224) {           // Wc2a 64x128
        int i = gid - 1452032, k = i >> 7, n = i & 127;
        o4[n * 64 + k] = f2bf(Wc2a[i]);
    } else if (gid < 1492992) {           // Wc2b 128x256
        int i = gid - 1460224, k = i >> 8, n = i & 255;
        o5[n * 128 + k] = f2bf(Wc2b[i]);
    } else if (gid < 1624064) {           // W6 256x512
        int i = gid - 1492992, k = i >> 9, n = i & 511;
        o6[n * 256 + k] = f2bf(W6[i]);
    } else if (gid < 1634064) {
        counts[gid - 1624064] = 0;
    } else if (gid < 1649424) {           // ZT pad tail [64][10000..10240)
        int i = gid - 1634064;
        Zt[(size_t)(i / 240) * KPAD + 10000 + (i % 240)] = 0;
    } else if (gid < 1710864) {           // H2T pad tail [256][10000..10240)
        int i = gid - 1649424;
        H2t[(size_t)(i / 240) * KPAD + 10000 + (i % 240)] = 0;
    }
}

// ---------------- CSR build ----------------
__global__ void hist_kernel(const int* __restrict__ rows, int* __restrict__ counts, int E) {
    int i = blockIdx.x * blockDim.x + threadIdx.x;
    if (i < E) atomicAdd(&counts[rows[i]], 1);
}

__global__ __launch_bounds__(1024)
void scan_kernel(const int* __restrict__ counts, int* __restrict__ starts,
                 int* __restrict__ cursor, int n) {
    __shared__ int buf[1024];
    int tid = threadIdx.x;
    int base = tid * 10;
    int v[10];
    int local = 0;
#pragma unroll
    for (int j = 0; j < 10; ++j) {
        int i = base + j;
        v[j] = (i < n) ? counts[i] : 0;
        local += v[j];
    }
    buf[tid] = local;
    __syncthreads();
    for (int off = 1; off < 1024; off <<= 1) {
        int t = (tid >= off) ? buf[tid - off] : 0;
        __syncthreads();
        buf[tid] += t;
        __syncthreads();
    }
    int run = buf[tid] - local;
#pragma unroll
    for (int j = 0; j < 10; ++j) {
        int i = base + j;
        if (i < n) { starts[i] = run; cursor[i] = run; run += v[j]; }
    }
    if (tid == 1023) starts[n] = buf[1023];
}

__global__ void scatter_kernel(const int* __restrict__ rows, const int* __restrict__ cols,
                               const float* __restrict__ vals, int* __restrict__ cursor,
                               int* __restrict__ cols_s, float* __restrict__ vals_s, int E) {
    int i = blockIdx.x * blockDim.x + threadIdx.x;
    if (i < E) {
        int pos = atomicAdd(&cursor[rows[i]], 1);
        cols_s[pos] = cols[i];
        vals_s[pos] = vals[i];
    }
}

// ---------------- SpMM: column-halved 2-pass gather (per-pass set 2.5 MB < 4 MB L2) ----------------
// grid (N, 2): blockIdx.y = column half; 64 threads x ushort2 = 128 cols.
__global__ __launch_bounds__(64)
void spmm_leaky_half(const int* __restrict__ starts, const int* __restrict__ cols_s,
                     const float* __restrict__ vals_s, const unsigned short* __restrict__ C1b,
                     const float* __restrict__ b1, unsigned short* __restrict__ Hb) {
    int r = blockIdx.x;
    int cbase = blockIdx.y * 128 + threadIdx.x * 2;
    float a0x = b1[cbase], a0y = b1[cbase + 1];
    float a1x = 0.f, a1y = 0.f, a2x = 0.f, a2y = 0.f, a3x = 0.f, a3y = 0.f;
    int s = starts[r], e = starts[r + 1];
    int p = s;
    for (; p + 4 <= e; p += 4) {
        int c0 = cols_s[p], c1 = cols_s[p + 1], c2 = cols_s[p + 2], c3 = cols_s[p + 3];
        float v0 = vals_s[p], v1 = vals_s[p + 1], v2 = vals_s[p + 2], v3 = vals_s[p + 3];
        ushort2 s0 = *(const ushort2*)(C1b + (size_t)c0 * 256 + cbase);
        ushort2 s1 = *(const ushort2*)(C1b + (size_t)c1 * 256 + cbase);
        ushort2 s2 = *(const ushort2*)(C1b + (size_t)c2 * 256 + cbase);
        ushort2 s3 = *(const ushort2*)(C1b + (size_t)c3 * 256 + cbase);
        a0x += v0 * bf2f(s0.x); a0y += v0 * bf2f(s0.y);
        a1x += v1 * bf2f(s1.x); a1y += v1 * bf2f(s1.y);
        a2x += v2 * bf2f(s2.x); a2y += v2 * bf2f(s2.y);
        a3x += v3 * bf2f(s3.x); a3y += v3 * bf2f(s3.y);
    }
    for (; p < e; ++p) {
        int c0 = cols_s[p];
        float v0 = vals_s[p];
        ushort2 s0 = *(const ushort2*)(C1b + (size_t)c0 * 256 + cbase);
        a0x += v0 * bf2f(s0.x); a0y += v0 * bf2f(s0.y);
    }
    ushort2 h;
    h.x = f2bf(leaky_f(a0x + a1x + a2x + a3x));
    h.y = f2bf(leaky_f(a0y + a1y + a2y + a3y));
    *(ushort2*)(Hb + (size_t)r * 256 + cbase) = h;
}

// ---------------- generic 64-tile MFMA GEMM ----------------
template<int ACT, int WF32, int WBF, int WTB>
__global__ __launch_bounds__(256)
void gemm_mfma(const unsigned short* __restrict__ A, const unsigned short* __restrict__ Bt,
               const float* __restrict__ bias, float* __restrict__ Cf,
               unsigned short* __restrict__ Cb, unsigned short* __restrict__ Ct,
               int ldt, int M, int N, int K) {
    __shared__ short sA[64][72];
    __shared__ short sB[64][72];
    const int bm = blockIdx.x * 64;
    const int bn = blockIdx.y * 64;
    const int tid = threadIdx.x;
    const int lane = tid & 63, wid = tid >> 6;
    const int wm = wid & 1, wn = wid >> 1;
    const int l15 = lane & 15, kg = lane >> 4;

    f32x4 acc[2][2];
#pragma unroll
    for (int i = 0; i < 2; i++)
#pragma unroll
        for (int j = 0; j < 2; j++) acc[i][j] = (f32x4){0.f, 0.f, 0.f, 0.f};

    for (int k0 = 0; k0 < K; k0 += 64) {
#pragma unroll
        for (int it = 0; it < 2; ++it) {
            int idx = tid + it * 256;
            int r = idx >> 3, s = idx & 7;
            int gm = bm + r;
            uint4 va = {0u, 0u, 0u, 0u};
            if (gm < M) va = *(const uint4*)(A + (size_t)gm * K + k0 + s * 8);
            *(uint4*)(&sA[r][s * 8]) = va;
            uint4 vb = *(const uint4*)(Bt + (size_t)(bn + r) * K + k0 + s * 8);
            *(uint4*)(&sB[r][s * 8]) = vb;
        }
        __syncthreads();
        bf16x8 a[2][2], b[2][2];
#pragma unroll
        for (int i = 0; i < 2; i++)
#pragma unroll
            for (int ks = 0; ks < 2; ++ks) {
                a[i][ks] = *(const bf16x8*)(&sA[wm * 32 + i * 16 + l15][kg * 8 + ks * 32]);
                b[i][ks] = *(const bf16x8*)(&sB[wn * 32 + i * 16 + l15][kg * 8 + ks * 32]);
            }
#pragma unroll
        for (int ks = 0; ks < 2; ++ks)
#pragma unroll
            for (int i = 0; i < 2; i++)
#pragma unroll
                for (int j = 0; j < 2; j++)
                    acc[i][j] = __builtin_amdgcn_mfma_f32_16x16x32_bf16(a[i][ks], b[j][ks], acc[i][j], 0, 0, 0);
        __syncthreads();
    }

#pragma unroll
    for (int i = 0; i < 2; i++) {
        int row0 = wm * 32 + i * 16 + kg * 4;
#pragma unroll
        for (int j = 0; j < 2; j++) {
            int col = bn + wn * 32 + j * 16 + l15;
            float bv = bias ? bias[col] : 0.f;
            ushort4 tw;
#pragma unroll
            for (int r = 0; r < 4; r++) {
                int grow = bm + row0 + r;
                float v = acc[i][j][r] + bv;
                if (ACT) v = leaky_f(v);
                if (WF32) { if (grow < M) Cf[(size_t)grow * N + col] = v; }
                if (WBF)  { if (grow < M) Cb[(size_t)grow * N + col] = f2bf(v); }
                if (WTB)  ((unsigned short*)&tw)[r] = f2bf(v);
            }
            if (WTB && (bm + row0) < M)
                *(ushort4*)(&Ct[(size_t)col * ldt + bm + row0]) = tw;
        }
    }
}

// ---------------- fused encoder tail: H -> T1 (LDS) -> z ----------------
__global__ __launch_bounds__(256)
void fused_enc(const unsigned short* __restrict__ H,   // [M][256]
               const unsigned short* __restrict__ Wa,  // [128][256]
               const unsigned short* __restrict__ Wb,  // [64][128]
               const float* __restrict__ ba, const float* __restrict__ bb,
               float* __restrict__ Zf, unsigned short* __restrict__ Zb,
               unsigned short* __restrict__ Zt, int M) {
    __shared__ short sA[64][72];
    __shared__ short sB[128][72];
    __shared__ short sT1[64][136];
    __shared__ short sWb[64][136];
    const int bm = blockIdx.x * 64;
    const int tid = threadIdx.x;
    const int lane = tid & 63, wid = tid >> 6;
    const int wm = wid & 1, wn = wid >> 1;
    const int l15 = lane & 15, kg = lane >> 4;

#pragma unroll
    for (int it = 0; it < 4; ++it) {
        int idx = tid + it * 256;
        int r = idx >> 4, s = idx & 15;
        *(uint4*)(&sWb[r][s * 8]) = *(const uint4*)(Wb + r * 128 + s * 8);
    }

    f32x4 accA[2][4];
#pragma unroll
    for (int i = 0; i < 2; i++)
#pragma unroll
        for (int j = 0; j < 4; j++) accA[i][j] = (f32x4){0.f, 0.f, 0.f, 0.f};

    for (int k0 = 0; k0 < 256; k0 += 64) {
#pragma unroll
        for (int it = 0; it < 2; ++it) {
            int idx = tid + it * 256;
            int r = idx >> 3, s = idx & 7;
            int gm = bm + r;
            uint4 va = {0u, 0u, 0u, 0u};
            if (gm < M) va = *(const uint4*)(H + (size_t)gm * 256 + k0 + s * 8);
            *(uint4*)(&sA[r][s * 8]) = va;
        }
#pragma unroll
        for (int it = 0; it < 4; ++it) {
            int idx = tid + it * 256;
            int r = idx >> 3, s = idx & 7;
            *(uint4*)(&sB[r][s * 8]) = *(const uint4*)(Wa + r * 256 + k0 + s * 8);
        }
        __syncthreads();
#pragma unroll
        for (int ks = 0; ks < 2; ++ks) {
            bf16x8 a[2], b[4];
#pragma unroll
            for (int i = 0; i < 2; i++)
                a[i] = *(const bf16x8*)(&sA[wm * 32 + i * 16 + l15][kg * 8 + ks * 32]);
#pragma unroll
            for (int j = 0; j < 4; j++)
                b[j] = *(const bf16x8*)(&sB[wn * 64 + j * 16 + l15][kg * 8 + ks * 32]);
#pragma unroll
            for (int i = 0; i < 2; i++)
#pragma unroll
                for (int j = 0; j < 4; j++)
                    accA[i][j] = __builtin_amdgcn_mfma_f32_16x16x32_bf16(a[i], b[j], accA[i][j], 0, 0, 0);
        }
        __syncthreads();
    }
#pragma unroll
    for (int i = 0; i < 2; i++) {
        int row0 = wm * 32 + i * 16 + kg * 4;
#pragma unroll
        for (int j = 0; j < 4; j++) {
            int col = wn * 64 + j * 16 + l15;
            float bv = ba[col];
#pragma unroll
            for (int r = 0; r < 4; r++)
                sT1[row0 + r][col] = f2bf(leaky_f(accA[i][j][r] + bv));
        }
    }
    __syncthreads();

    f32x4 accB[2][2];
#pragma unroll
    for (int i = 0; i < 2; i++)
#pragma unroll
        for (int j = 0; j < 2; j++) accB[i][j] = (f32x4){0.f, 0.f, 0.f, 0.f};
#pragma unroll
    for (int kc = 0; kc < 4; ++kc) {
        bf16x8 a[2], b[2];
#pragma unroll
        for (int i = 0; i < 2; i++)
            a[i] = *(const bf16x8*)(&sT1[wm * 32 + i * 16 + l15][kc * 32 + kg * 8]);
#pragma unroll
        for (int j = 0; j < 2; j++)
            b[j] = *(const bf16x8*)(&sWb[wn * 32 + j * 16 + l15][kc * 32 + kg * 8]);
#pragma unroll
        for (int i = 0; i < 2; i++)
#pragma unroll
            for (int j = 0; j < 2; j++)
                accB[i][j] = __builtin_amdgcn_mfma_f32_16x16x32_bf16(a[i], b[j], accB[i][j], 0, 0, 0);
    }
#pragma unroll
    for (int i = 0; i < 2; i++) {
        int row0 = wm * 32 + i * 16 + kg * 4;
#pragma unroll
        for (int j = 0; j < 2; j++) {
            int col = wn * 32 + j * 16 + l15;
            float bv = bb[col];
            ushort4 tw;
#pragma unroll
            for (int r = 0; r < 4; r++) {
                int grow = bm + row0 + r;
                float v = accB[i][j][r] + bv;
                if (grow < M) {
                    Zf[(size_t)grow * 64 + col] = v;
                    Zb[(size_t)grow * 64 + col] = f2bf(v);
                }
                ((unsigned short*)&tw)[r] = f2bf(v);
            }
            if ((bm + row0) < M)
                *(ushort4*)(&Zt[(size_t)col * KPAD + bm + row0]) = tw;
        }
    }
}

// ---------------- fused decoder head: z -> T2 (LDS) -> H2^T ----------------
__global__ __launch_bounds__(256)
void fused_dec(const unsigned short* __restrict__ Z,   // [M][64]
               const unsigned short* __restrict__ Wa,  // [128][64]
               const unsigned short* __restrict__ Wb,  // [256][128]
               const float* __restrict__ ba, const float* __restrict__ bb,
               unsigned short* __restrict__ H2t, int M) {
    __shared__ short sA[64][72];
    __shared__ short sB[128][72];
    __shared__ short sT2[64][136];
    __shared__ short sB2[256][72];
    const int bm = blockIdx.x * 64;
    const int tid = threadIdx.x;
    const int lane = tid & 63, wid = tid >> 6;
    const int wm = wid & 1, wn = wid >> 1;
    const int l15 = lane & 15, kg = lane >> 4;

#pragma unroll
    for (int it = 0; it < 2; ++it) {
        int idx = tid + it * 256;
        int r = idx >> 3, s = idx & 7;
        int gm = bm + r;
        uint4 va = {0u, 0u, 0u, 0u};
        if (gm < M) va = *(const uint4*)(Z + (size_t)gm * 64 + s * 8);
        *(uint4*)(&sA[r][s * 8]) = va;
    }
#pragma unroll
    for (int it = 0; it < 4; ++it) {
        int idx = tid + it * 256;
        int r = idx >> 3, s = idx & 7;
        *(uint4*)(&sB[r][s * 8]) = *(const uint4*)(Wa + r * 64 + s * 8);
    }
    __syncthreads();
    f32x4 accA[2][4];
#pragma unroll
    for (int i = 0; i < 2; i++)
#pragma unroll
        for (int j = 0; j < 4; j++) accA[i][j] = (f32x4){0.f, 0.f, 0.f, 0.f};
#pragma unroll
    for (int ks = 0; ks < 2; ++ks) {
        bf16x8 a[2], b[4];
#pragma unroll
        for (int i = 0; i < 2; i++)
            a[i] = *(const bf16x8*)(&sA[wm * 32 + i * 16 + l15][kg * 8 + ks * 32]);
#pragma unroll
        for (int j = 0; j < 4; j++)
            b[j] = *(const bf16x8*)(&sB[wn * 64 + j * 16 + l15][kg * 8 + ks * 32]);
#pragma unroll
        for (int i = 0; i < 2; i++)
#pragma unroll
            for (int j = 0; j < 4; j++)
                accA[i][j] = __builtin_amdgcn_mfma_f32_16x16x32_bf16(a[i], b[j], accA[i][j], 0, 0, 0);
    }
    __syncthreads();
#pragma unroll
    for (int i = 0; i < 2; i++) {
        int row0 = wm * 32 + i * 16 + kg * 4;
#pragma unroll
        for (int j = 0; j < 4; j++) {
            int col = wn * 64 + j * 16 + l15;
            float bv = ba[col];
#pragma unroll
            for (int r = 0; r < 4; r++)
                sT2[row0 + r][col] = f2bf(leaky_f(accA[i][j][r] + bv));
        }
    }
    __syncthreads();

    f32x4 accB[2][8];
#pragma unroll
    for (int i = 0; i < 2; i++)
#pragma unroll
        for (int j = 0; j < 8; j++) accB[i][j] = (f32x4){0.f, 0.f, 0.f, 0.f};
    for (int k0 = 0; k0 < 128; k0 += 64) {
#pragma unroll
        for (int it = 0; it < 8; ++it) {
            int idx = tid + it * 256;
            int r = idx >> 3, s = idx & 7;
            *(uint4*)(&sB2[r][s * 8]) = *(const uint4*)(Wb + r * 128 + k0 + s * 8);
        }
        __syncthreads();
#pragma unroll
        for (int ks = 0; ks < 2; ++ks) {
            bf16x8 a[2], b[8];
#pragma unroll
            for (int i = 0; i < 2; i++)
                a[i] = *(const bf16x8*)(&sT2[wm * 32 + i * 16 + l15][k0 + ks * 32 + kg * 8]);
#pragma unroll
            for (int j = 0; j < 8; j++)
                b[j] = *(const bf16x8*)(&sB2[wn * 128 + j * 16 + l15][kg * 8 + ks * 32]);
#pragma unroll
            for (int i = 0; i < 2; i++)
#pragma unroll
                for (int j = 0; j < 8; j++)
                    accB[i][j] = __builtin_amdgcn_mfma_f32_16x16x32_bf16(a[i], b[j], accB[i][j], 0, 0, 0);
        }
        __syncthreads();
    }
#pragma unroll
    for (int i = 0; i < 2; i++) {
        int row0 = wm * 32 + i * 16 + kg * 4;
#pragma unroll
        for (int j = 0; j < 8; j++) {
            int col = wn * 128 + j * 16 + l15;
            float bv = bb[col];
            ushort4 tw;
#pragma unroll
            for (int r = 0; r < 4; r++)
                ((unsigned short*)&tw)[r] = f2bf(leaky_f(accB[i][j][r] + bv));
            if ((bm + row0) < M)
                *(ushort4*)(&H2t[(size_t)col * KPAD + bm + row0]) = tw;
        }
    }
}

// ---------------- S2 split-K MFMA: 40 splits of 256 ----------------
__global__ __launch_bounds__(256)
void sgemm_sk(const unsigned short* __restrict__ Zt, const unsigned short* __restrict__ H2t,
              float* __restrict__ part) {
    __shared__ short sA[64][72];
    __shared__ short sB[64][72];
    const int bn = blockIdx.x * 64;
    const int kc = blockIdx.y;
    const int tid = threadIdx.x;
    const int lane = tid & 63, wid = tid >> 6;
    const int wm = wid & 1, wn = wid >> 1;
    const int l15 = lane & 15, kg = lane >> 4;

    f32x4 acc[2][2];
#pragma unroll
    for (int i = 0; i < 2; i++)
#pragma unroll
        for (int j = 0; j < 2; j++) acc[i][j] = (f32x4){0.f, 0.f, 0.f, 0.f};

    for (int kk = 0; kk < 4; ++kk) {
        int k0 = kc * 256 + kk * 64;
#pragma unroll
        for (int it = 0; it < 2; ++it) {
            int idx = tid + it * 256;
            int r = idx >> 3, s = idx & 7;
            *(uint4*)(&sA[r][s * 8]) = *(const uint4*)(Zt + (size_t)r * KPAD + k0 + s * 8);
            *(uint4*)(&sB[r][s * 8]) = *(const uint4*)(H2t + (size_t)(bn + r) * KPAD + k0 + s * 8);
        }
        __syncthreads();
        bf16x8 a[2][2], b[2][2];
#pragma unroll
        for (int i = 0; i < 2; i++)
#pragma unroll
            for (int ks = 0; ks < 2; ++ks) {
                a[i][ks] = *(const bf16x8*)(&sA[wm * 32 + i * 16 + l15][kg * 8 + ks * 32]);
                b[i][ks] = *(const bf16x8*)(&sB[wn * 32 + i * 16 + l15][kg * 8 + ks * 32]);
            }
#pragma unroll
        for (int ks = 0; ks < 2; ++ks)
#pragma unroll
            for (int i = 0; i < 2; i++)
#pragma unroll
                for (int j = 0; j < 2; j++)
                    acc[i][j] = __builtin_amdgcn_mfma_f32_16x16x32_bf16(a[i][ks], b[j][ks], acc[i][j], 0, 0, 0);
        __syncthreads();
    }
#pragma unroll
    for (int i = 0; i < 2; i++) {
        int row0 = wm * 32 + i * 16 + kg * 4;
#pragma unroll
        for (int j = 0; j < 2; j++) {
            int col = bn + wn * 32 + j * 16 + l15;
#pragma unroll
            for (int r = 0; r < 4; r++)
                part[((size_t)kc * 64 + row0 + r) * 256 + col] = acc[i][j][r];
        }
    }
}

// reduce 40 partials -> S2 bf16 [64][256]
__global__ void reduce_S2(const float* __restrict__ part, unsigned short* __restrict__ S2b) {
    int i = blockIdx.x * blockDim.x + threadIdx.x;
    if (i < 64 * 256) {
        float s = 0.f;
#pragma unroll
        for (int c = 0; c < 40; ++c) s += part[(size_t)c * (64 * 256) + i];
        S2b[i] = f2bf(s);
    }
}

// ---------------- launch ----------------
extern "C" void kernel_launch(void* const* d_in, const int* in_sizes, int n_in,
                              void* d_out, int out_size, void* d_ws, size_t ws_size,
                              hipStream_t stream) {
    const float* x    = (const float*)d_in[0];
    const int*   rows = (const int*)d_in[1];
    const int*   cols = (const int*)d_in[2];
    const float* vals = (const float*)d_in[3];
    const float* W1   = (const float*)d_in[4];
    const float* b1   = (const float*)d_in[5];
    const float* Wc1a = (const float*)d_in[6];
    const float* bc1a = (const float*)d_in[7];
    const float* Wc1b = (const float*)d_in[8];
    const float* bc1b = (const float*)d_in[9];
    const float* Wc2a = (const float*)d_in[10];
    const float* bc2a = (const float*)d_in[11];
    const float* Wc2b = (const float*)d_in[12];
    const float* bc2b = (const float*)d_in[13];
    const float* W6   = (const float*)d_in[14];
    const float* b6   = (const float*)d_in[15];

    const int N = NROWS;
    const int E = in_sizes[1];

    float* ws = (float*)d_ws;
    unsigned short* XHI  = (unsigned short*)(ws + 0);         // [10000][512]
    unsigned short* C1b  = (unsigned short*)(ws + 2560000);   // [10000][256]
    unsigned short* HHI  = (unsigned short*)(ws + 3840000);   // [10000][256]
    unsigned short* ZHI  = (unsigned short*)(ws + 5120000);   // [10000][64]
    unsigned short* ZT   = (unsigned short*)(ws + 5440000);   // [64][10240]
    unsigned short* H2T  = (unsigned short*)(ws + 5767680);   // [256][10240]
    float*          PART = ws + 7078400;                      // [40][64][256]
    unsigned short* S2B  = (unsigned short*)(ws + 7733760);   // [64][256]
    unsigned short* W6ST = (unsigned short*)(ws + 7741952);   // [512][64]
    unsigned short* W1T   = (unsigned short*)(ws + 7758336);  // [256][512]
    unsigned short* WC1AT = (unsigned short*)(ws + 7823872);  // [128][256]
    unsigned short* WC1BT = (unsigned short*)(ws + 7840256);  // [64][128]
    unsigned short* WC2AT = (unsigned short*)(ws + 7844352);  // [128][64]
    unsigned short* WC2BT = (unsigned short*)(ws + 7848448);  // [256][128]
    unsigned short* W6T   = (unsigned short*)(ws + 7864832);  // [512][256]

    int*   counts = (int*)(ws + 7930368);
    int*   starts = counts + 10000;
    int*   cursor = starts + 10001;
    int*   cols_s = cursor + 10000;
    float* vals_s = (float*)(cols_s + 320000);

    float* Out = (float*)d_out;
    float* Zp  = (float*)d_out + 5120000;

    const int GX = (N + 63) / 64;  // 157

    conv_all<<<6683, 256, 0, stream>>>(x, W1, Wc1a, Wc1b, Wc2a, Wc2b, W6, XHI,
                                       W1T, WC1AT, WC1BT, WC2AT, WC2BT, W6T,
                                       counts, ZT, H2T);

    hist_kernel<<<(E + 255) / 256, 256, 0, stream>>>(rows, counts, E);
    scan_kernel<<<1, 1024, 0, stream>>>(counts, starts, cursor, N);
    scatter_kernel<<<(E + 255) / 256, 256, 0, stream>>>(rows, cols, vals, cursor, cols_s, vals_s, E);

    // C1 = x @ W1 -> bf16 (round-7 64-tile)
    gemm_mfma<0,0,1,0><<<dim3(GX, 4), 256, 0, stream>>>(XHI, W1T, nullptr,
                                                        nullptr, C1b, nullptr, 0, N, 256, 512);

    // H = leaky(spmm + b1) -> bf16 (column-halved 2-pass gather)
    spmm_leaky_half<<<dim3(N, 2), 64, 0, stream>>>(starts, cols_s, vals_s, C1b, b1, HHI);

    // z = leaky(H@Wc1a+b)@Wc1b + b -> Zp f32, ZHI bf16, ZT bf16
    fused_enc<<<GX, 256, 0, stream>>>(HHI, WC1AT, WC1BT, bc1a, bc1b, Zp, ZHI, ZT, N);

    // H2^T -> bf16 [256][KPAD]
    fused_dec<<<GX, 256, 0, stream>>>(ZHI, WC2AT, WC2BT, bc2a, bc2b, H2T, N);

    // S2 = z^T @ H2 (split-K 40) -> PART -> S2B [64][256]
    sgemm_sk<<<dim3(4, 40), 256, 0, stream>>>(ZT, H2T, PART);
    reduce_S2<<<64, 256, 0, stream>>>(PART, S2B);

    // W6S = S2 @ W6 -> W6ST [512][64]
    gemm_mfma<0,0,0,1><<<dim3(1, 8), 256, 0, stream>>>(S2B, W6T, nullptr,
                                                       nullptr, nullptr, W6ST, 64, 64, 512, 256);

    // out = z @ W6S + b6 -> f32 (round-7 64-tile)
    gemm_mfma<0,1,0,0><<<dim3(GX, 8), 256, 0, stream>>>(ZHI, W6ST, b6,
                                                        Out, nullptr, nullptr, 0, N, 512, 64);
}